// Round 6
// baseline (462.964 us; speedup 1.0000x reference)
//
#include <hip/hip_runtime.h>

// LSS voxel pooling: N_POINTS=692736, C=64, B=4, NX=256, NY=256, NZ=1 (gz==0)
// final[b, c, 0, ix, iy] = sum over points at (ix,iy,b) of x[:, c]
// out flat: ((b*64 + c)*256 + ix)*256 + iy   (fp32, 64 MB)
//
// Strategy v6 (resubmit; round-5 run died to container infra, not the kernel):
// SCATTER-then-REDUCE (invert the random stream direction).
//   v2/v3/v5 post-mortem: every gather variant caps at ~2.1 TB/s because
//   random READS are limited by outstanding-miss slots x miss latency.
//   Random WRITES drain through write buffers (no MSHR hold) — the harness's
//   own 709 MB fill streams at 6.75 TB/s.  So:
//     K1 scatter: sequential x+geom read, 1 atomic/point, copy each 256 B row
//                 to featbuf[v][slot]  (random 256 B WRITES).
//     K2 reduce:  ascending sparse-sequential featbuf read, sum slots,
//                 LDS transpose, coalesced out write.
//   Fill pass is merged into K1 (geom read once; no separate fill kernel).

#define NPTS   692736          // = 10824 * 64 exactly
#define CFEAT  64
#define NXV    256
#define NYV    256
#define NBAT   4
#define NVOX   (NBAT * NXV * NYV)   // 262144
#define CAP    8                    // slots/voxel; P(cnt>8) ~ 0.19% (lam=2.64)

typedef float f32x4 __attribute__((ext_vector_type(4)));

// ws layout (bytes; ws_size ~ 676 MiB per harness poison fill):
//   [0,      1 MB)   count    (memset to 0 each call)
//   [1 MB,   +4 B)   ovf_cnt  (memset to 0, same memset)
//   [1 MB+64,8 MB)   ovf pairs (v, p) — ~458K pair capacity
//   [8 MB, 8 MB+512 MiB) featbuf[NVOX][CAP][CFEAT] fp32

// --- K1: scatter rows into per-voxel slots ---------------------------------
// 256 threads = 64 points x 4 quarter-rows. Reads fully sequential.
__global__ __launch_bounds__(256) void scatter_kernel(
    const float* __restrict__ x, const int* __restrict__ geom,
    int* __restrict__ count, float* __restrict__ featbuf,
    int* __restrict__ ovf_cnt, int* __restrict__ ovf)
{
    const int t = threadIdx.x;
    const int p = blockIdx.x * 64 + (t >> 2);   // grid exact: 10824*64 == NPTS
    const int q = t & 3;                        // quarter-row: 16 floats

    // sequential quarter-row load (issue before the atomic; independent)
    const f32x4* src = (const f32x4*)(x + (size_t)p * CFEAT + q * 16);
    f32x4 r0 = __builtin_nontemporal_load(src + 0);
    f32x4 r1 = __builtin_nontemporal_load(src + 1);
    f32x4 r2 = __builtin_nontemporal_load(src + 2);
    f32x4 r3 = __builtin_nontemporal_load(src + 3);

    const int4 g = *(const int4*)(geom + (size_t)p * 4);   // gx, gy, gz, gb
    const int v  = (g.w * NXV + g.x) * NYV + g.y;

    int pos = 0;
    if (q == 0) {
        pos = atomicAdd(&count[v], 1);
        if (pos >= CAP) {                        // 0.19% of voxels
            int j = atomicAdd(ovf_cnt, 1);
            ovf[2 * j]     = v;
            ovf[2 * j + 1] = p;
        }
    }
    pos = __shfl(pos, (t & 63) & ~3, 64);        // broadcast within quad

    if (pos < CAP) {
        f32x4* dst = (f32x4*)(featbuf + ((size_t)v * CAP + pos) * CFEAT + q * 16);
        __builtin_nontemporal_store(r0, dst + 0);
        __builtin_nontemporal_store(r1, dst + 1);
        __builtin_nontemporal_store(r2, dst + 2);
        __builtin_nontemporal_store(r3, dst + 3);
    }
}

// --- K2: per-voxel slot reduction + transposed coalesced writeout -----------
// Block = 64 consecutive voxels (fixed b, ix; iy0..iy0+63). 256 threads =
// 64 voxels x 4 quarter-rows. featbuf reads: ascending, contiguous from
// slot 0 per voxel -> DRAM-row friendly. Out: 256 B bursts via LDS transpose.
__global__ __launch_bounds__(256) void reduce_kernel(
    const float* __restrict__ x, const int* __restrict__ count,
    const float* __restrict__ featbuf, const int* __restrict__ ovf_cnt,
    const int* __restrict__ ovf, float* __restrict__ out)
{
    __shared__ float lds[64][65];                // +1 pad: conflict-free readout

    const int t     = threadIdx.x;
    const int vl    = t >> 2;                    // local voxel 0..63
    const int q     = t & 3;                     // quarter-row
    const int vbase = blockIdx.x * 64;
    const int v     = vbase + vl;

    const int cnt = count[v];
    const int n   = cnt < CAP ? cnt : CAP;

    const f32x4* base = (const f32x4*)(featbuf + (size_t)v * CAP * CFEAT + q * 16);
    f32x4 a0 = {}, a1 = {}, a2 = {}, a3 = {};
    for (int k = 0; k < n; ++k) {                // addresses affine in k: pipelines
        const f32x4* s = base + (size_t)k * (CFEAT / 4);
        a0 += __builtin_nontemporal_load(s + 0);
        a1 += __builtin_nontemporal_load(s + 1);
        a2 += __builtin_nontemporal_load(s + 2);
        a3 += __builtin_nontemporal_load(s + 3);
    }

    if (cnt > CAP) {                             // rare slow path (L2-cached scan)
        int no = *ovf_cnt;
        for (int j = 0; j < no; ++j) {
            if (ovf[2 * j] == v) {
                const f32x4* s =
                    (const f32x4*)(x + (size_t)ovf[2 * j + 1] * CFEAT + q * 16);
                a0 += s[0]; a1 += s[1]; a2 += s[2]; a3 += s[3];
            }
        }
    }

    // stash into LDS tile [iy_local][c]
    float* row = &lds[vl][q * 16];
    #pragma unroll
    for (int m = 0; m < 4; ++m) {
        row[0 + m]  = a0[m];
        row[4 + m]  = a1[m];
        row[8 + m]  = a2[m];
        row[12 + m] = a3[m];
    }
    __syncthreads();

    // writeout: wave w covers channel c = i*4 + w; 64 lanes = 64 consecutive iy
    const int b   = vbase >> 16;
    const int ix  = (vbase >> 8) & 255;
    const int iy0 = vbase & 255;                 // multiple of 64
    const int w   = t >> 6, l = t & 63;
    const size_t obase = (size_t)b * CFEAT * (NXV * NYV)
                       + (size_t)ix * NYV + iy0 + l;
    #pragma unroll
    for (int i = 0; i < 16; ++i) {
        int c = i * 4 + w;
        __builtin_nontemporal_store(lds[l][c],
            out + obase + (size_t)c * (NXV * NYV));
    }
}

extern "C" void kernel_launch(void* const* d_in, const int* in_sizes, int n_in,
                              void* d_out, int out_size, void* d_ws, size_t ws_size,
                              hipStream_t stream) {
    const float* x  = (const float*)d_in[0];   // fp32 [NPTS,64]
    const int* geom = (const int*)d_in[1];     // [NPTS,4]
    float* out      = (float*)d_out;           // fp32 [4,64,256,256]

    char* w = (char*)d_ws;
    int*   count   = (int*)(w);
    int*   ovf_cnt = (int*)(w + (1u << 20));
    int*   ovf     = (int*)(w + (1u << 20) + 64);
    float* featbuf = (float*)(w + (8u << 20));   // 512 MiB

    // zero count + ovf_cnt in one memset
    hipMemsetAsync(w, 0, (1u << 20) + 64, stream);

    scatter_kernel<<<NPTS / 64, 256, 0, stream>>>(x, geom, count, featbuf,
                                                  ovf_cnt, ovf);
    reduce_kernel <<<NVOX / 64, 256, 0, stream>>>(x, count, featbuf,
                                                  ovf_cnt, ovf, out);
}